// Round 13
// baseline (407.410 us; speedup 1.0000x reference)
//
#include <hip/hip_runtime.h>
#include <hip/hip_bf16.h>

#define NN 100000
#define NE 1600000
#define NG 512
#define HID 128
#define PPART 391  // ceil(NN/256) partitions of 256 nodes
#define EPB 4096   // edges per block in k_hist/k_part

typedef __attribute__((ext_vector_type(8))) short short8;
typedef __attribute__((ext_vector_type(4))) float floatx4;

__device__ inline ushort f2bf(float f) {
  uint u = __float_as_uint(f);
  u += 0x7fff + ((u >> 16) & 1);
  return (ushort)(u >> 16);
}
__device__ inline uint pack2(float lo, float hi) {
  return (uint)f2bf(lo) | ((uint)f2bf(hi) << 16);
}
__device__ inline float bflo(uint u) { return __uint_as_float(u << 16); }
__device__ inline float bfhi(uint u) { return __uint_as_float(u & 0xffff0000u); }

// ---------------- per-partition histogram (LDS-absorbed atomics) ----------------
__global__ __launch_bounds__(256) void k_hist(const int* __restrict__ dst,
                                              int* __restrict__ phist) {
  __shared__ int h[PPART];
  int t = threadIdx.x;
  for (int i = t; i < PPART; i += 256) h[i] = 0;
  __syncthreads();
  int e0 = blockIdx.x * EPB;
#pragma unroll
  for (int l = 0; l < 16; ++l) {
    int e = e0 + l * 256 + t;
    if (e < NE) atomicAdd(&h[dst[e] >> 8], 1);
  }
  __syncthreads();
  for (int i = t; i < PPART; i += 256)
    if (h[i]) atomicAdd(&phist[i], h[i]);
}

// ---------------- scan partition sizes -> pbase[0..PPART], pcur ----------------
__global__ __launch_bounds__(512) void k_pscan(const int* __restrict__ phist,
                                               int* __restrict__ pbase,
                                               int* __restrict__ pcur) {
  __shared__ int ws[8];
  int t = threadIdx.x, lane = t & 63, wid = t >> 6;
  int v = (t < PPART) ? phist[t] : 0;
  int iv = v;
  for (int o = 1; o < 64; o <<= 1) {
    int n = __shfl_up(iv, o, 64);
    if (lane >= o) iv += n;
  }
  if (lane == 63) ws[wid] = iv;
  __syncthreads();
  int add = 0;
#pragma unroll
  for (int w = 0; w < 8; ++w) add += (w < wid) ? ws[w] : 0;
  if (t < PPART) {
    int b = iv - v + add;
    pbase[t] = b;
    pcur[t] = b;
  }
  if (t == 0) {
    int tot = 0;
#pragma unroll
    for (int w = 0; w < 8; ++w) tot += ws[w];
    pbase[PPART] = tot;
  }
}

// ---------------- phase A: scatter packed edges into partition windows ----------------
__global__ __launch_bounds__(256) void k_part(const int* __restrict__ src,
                                              const int* __restrict__ dst,
                                              int* __restrict__ pcur,
                                              uint* __restrict__ pedge) {
  __shared__ int hist[PPART];
  __shared__ int base[PPART];
  int t = threadIdx.x;
  for (int i = t; i < PPART; i += 256) hist[i] = 0;
  __syncthreads();
  int e0 = blockIdx.x * EPB;
  int d_[16];
#pragma unroll
  for (int l = 0; l < 16; ++l) {
    int e = e0 + l * 256 + t;
    if (e < NE) {
      int d = dst[e];
      d_[l] = d;
      atomicAdd(&hist[d >> 8], 1);
    } else {
      d_[l] = -1;
    }
  }
  __syncthreads();
  for (int i = t; i < PPART; i += 256) {
    int h = hist[i];
    base[i] = h ? atomicAdd(&pcur[i], h) : 0;
  }
  __syncthreads();
#pragma unroll
  for (int l = 0; l < 16; ++l) {
    int e = e0 + l * 256 + t;
    if (e < NE) {
      int d = d_[l];
      int s = src[e];
      int pos = atomicAdd(&base[d >> 8], 1);
      pedge[pos] = (uint)s | ((uint)(d & 255) << 24);
    }
  }
}

// ---------------- phase B1: per-partition count+scan -> offsets, dinv ----------------
__global__ __launch_bounds__(256) void k_cnt2(const int* __restrict__ pbase,
                                              const uint* __restrict__ pedge,
                                              int* __restrict__ offsets,
                                              float* __restrict__ dinv) {
  __shared__ int cnt_s[256];
  __shared__ int ws[4];
  int p = blockIdx.x;
  int n0 = p << 8;
  int t = threadIdx.x;
  int lim = NN - n0; if (lim > 256) lim = 256;
  int s = pbase[p], e = pbase[p + 1];
  cnt_s[t] = 0;
  __syncthreads();
  for (int i = s + t; i < e; i += 256) atomicAdd(&cnt_s[pedge[i] >> 24], 1);
  __syncthreads();
  int v = cnt_s[t];
  int lane = t & 63, wid = t >> 6;
  int iv = v;
  for (int o = 1; o < 64; o <<= 1) {
    int n = __shfl_up(iv, o, 64);
    if (lane >= o) iv += n;
  }
  if (lane == 63) ws[wid] = iv;
  __syncthreads();
  int add = 0;
#pragma unroll
  for (int w = 0; w < 4; ++w) add += (w < wid) ? ws[w] : 0;
  int excl = iv - v + add;
  if (t < lim) {
    offsets[n0 + t] = s + excl;
    dinv[n0 + t] = 1.0f / sqrtf((float)(v + 1));
  }
  if (p == PPART - 1 && t == 0) offsets[NN] = NE;
}

// ---------------- phase B2: place edges -> emeta {src, bits(dinv[src])} ----------------
__global__ __launch_bounds__(256) void k_place(const int* __restrict__ pbase,
                                               const uint* __restrict__ pedge,
                                               const int* __restrict__ offsets,
                                               const float* __restrict__ dinv,
                                               int2* __restrict__ emeta) {
  __shared__ int cur[256];
  int p = blockIdx.x;
  int n0 = p << 8;
  int t = threadIdx.x;
  int lim = NN - n0; if (lim > 256) lim = 256;
  if (t < lim) cur[t] = offsets[n0 + t];
  __syncthreads();
  int s = pbase[p], e = pbase[p + 1];
  for (int i = s + t; i < e; i += 256) {
    uint pv = pedge[i];
    int srcn = (int)(pv & 0xFFFFFFu);
    int pos = atomicAdd(&cur[pv >> 24], 1);
    int2 m;
    m.x = srcn;
    m.y = __float_as_int(dinv[srcn]);
    emeta[pos] = m;
  }
}

// ---------------- prep W: f32 [128,128] -> bf16 W^T swizzled ----------------
__global__ __launch_bounds__(128) void k_prepW(const float* __restrict__ W,
                                               ushort* __restrict__ wt) {
  int c = blockIdx.x;
  int r = threadIdx.x;
  float v = W[r * 128 + c];
  wt[c * 128 + (((r >> 3) ^ (c & 15)) << 3) + (r & 7)] = f2bf(v);
}

// ---------------- bf16 MFMA GEMM (bf16 A): H = X @ W ----------------
__global__ __launch_bounds__(256) void k_gemm(const ushort* __restrict__ Xb,
                                              const ushort* __restrict__ wt,
                                              ushort* __restrict__ Hb) {
  __shared__ ushort sW[128 * 128];
  int t = threadIdx.x;
#pragma unroll
  for (int l = 0; l < 8; ++l) {
    int idx = t + l * 256;
    ((uint4*)sW)[idx] = ((const uint4*)wt)[idx];
  }
  __syncthreads();
  int wid = t >> 6, lane = t & 63;
  int row0 = blockIdx.x * 64 + wid * 16;
  int arow = row0 + (lane & 15);
  if (arow >= NN) arow = NN - 1;
  const ushort* aptr = Xb + (size_t)arow * 128 + ((lane >> 4) * 8);
  floatx4 acc[8];
#pragma unroll
  for (int n = 0; n < 8; ++n) acc[n] = (floatx4)(0.f);
#pragma unroll
  for (int kb = 0; kb < 4; ++kb) {
    short8 a = *(const short8*)(aptr + kb * 32);
    int kslot = kb * 4 + (lane >> 4);
#pragma unroll
    for (int n = 0; n < 8; ++n) {
      int col = n * 16 + (lane & 15);
      const ushort* bp = sW + col * 128 + ((kslot ^ (col & 15)) << 3);
      short8 b = *(const short8*)bp;
      acc[n] = __builtin_amdgcn_mfma_f32_16x16x32_bf16(a, b, acc[n], 0, 0, 0);
    }
  }
  int srow_base = row0 + (lane >> 4) * 4;
#pragma unroll
  for (int r = 0; r < 4; ++r) {
    int grow = srow_base + r;
    if (grow < NN) {
      ushort* out = Hb + (size_t)grow * 128 + (lane & 15);
#pragma unroll
      for (int n = 0; n < 8; ++n) out[n * 16] = f2bf(acc[n][r]);
    }
  }
}

// ---------------- bf16 MFMA GEMM, f32 A input (layer 1; fuses the cast) ----------------
__global__ __launch_bounds__(256) void k_gemmf(const float* __restrict__ Xf,
                                               const ushort* __restrict__ wt,
                                               ushort* __restrict__ Hb) {
  __shared__ ushort sW[128 * 128];
  int t = threadIdx.x;
#pragma unroll
  for (int l = 0; l < 8; ++l) {
    int idx = t + l * 256;
    ((uint4*)sW)[idx] = ((const uint4*)wt)[idx];
  }
  __syncthreads();
  int wid = t >> 6, lane = t & 63;
  int row0 = blockIdx.x * 64 + wid * 16;
  int arow = row0 + (lane & 15);
  if (arow >= NN) arow = NN - 1;
  const float* aptr = Xf + (size_t)arow * 128 + ((lane >> 4) * 8);
  floatx4 acc[8];
#pragma unroll
  for (int n = 0; n < 8; ++n) acc[n] = (floatx4)(0.f);
#pragma unroll
  for (int kb = 0; kb < 4; ++kb) {
    float4 f0 = *(const float4*)(aptr + kb * 32);
    float4 f1 = *(const float4*)(aptr + kb * 32 + 4);
    union { uint4 u; short8 s; } av;
    av.u.x = pack2(f0.x, f0.y);
    av.u.y = pack2(f0.z, f0.w);
    av.u.z = pack2(f1.x, f1.y);
    av.u.w = pack2(f1.z, f1.w);
    short8 a = av.s;
    int kslot = kb * 4 + (lane >> 4);
#pragma unroll
    for (int n = 0; n < 8; ++n) {
      int col = n * 16 + (lane & 15);
      const ushort* bp = sW + col * 128 + ((kslot ^ (col & 15)) << 3);
      short8 b = *(const short8*)bp;
      acc[n] = __builtin_amdgcn_mfma_f32_16x16x32_bf16(a, b, acc[n], 0, 0, 0);
    }
  }
  int srow_base = row0 + (lane >> 4) * 4;
#pragma unroll
  for (int r = 0; r < 4; ++r) {
    int grow = srow_base + r;
    if (grow < NN) {
      ushort* out = Hb + (size_t)grow * 128 + (lane & 15);
#pragma unroll
      for (int n = 0; n < 8; ++n) out[n * 16] = f2bf(acc[n][r]);
    }
  }
}

// ---------------- pull aggregation: 16-deep gather batches ----------------
// 16-lane group per node; each lane redundantly loads the chunk's 16 emeta
// entries (1-2 cache lines, L1 broadcast) -> chain is meta -> gather only.
__global__ __launch_bounds__(256) void k_agg(const ushort* __restrict__ H,
                                             const float* __restrict__ bias,
                                             const float* __restrict__ dinv,
                                             const int* __restrict__ offsets,
                                             const int2* __restrict__ emeta,
                                             ushort* __restrict__ Hout, int do_relu) {
  int node = blockIdx.x * 16 + (threadIdx.x >> 4);
  if (node >= NN) return;
  int c8 = threadIdx.x & 15;  // 16B slot; channels c8*8 .. c8*8+7
  float di = dinv[node];
  int s = offsets[node], e = offsets[node + 1];
  float acc[8];
#pragma unroll
  for (int j = 0; j < 8; ++j) acc[j] = 0.f;
  for (int i = s; i < e; i += 16) {
    int sxu[16];
    float wu[16];
#pragma unroll
    for (int u = 0; u < 16; ++u) {
      int idx = i + u;
      bool vld = idx < e;
      int2 m = emeta[vld ? idx : s];
      sxu[u] = m.x;
      wu[u] = vld ? __int_as_float(m.y) : 0.0f;
    }
    uint4 vx[16];
#pragma unroll
    for (int u = 0; u < 16; ++u)
      vx[u] = *((const uint4*)(H + (size_t)sxu[u] * 128) + c8);
#pragma unroll
    for (int u = 0; u < 16; ++u) {
      acc[0] += bflo(vx[u].x) * wu[u];
      acc[1] += bfhi(vx[u].x) * wu[u];
      acc[2] += bflo(vx[u].y) * wu[u];
      acc[3] += bfhi(vx[u].y) * wu[u];
      acc[4] += bflo(vx[u].z) * wu[u];
      acc[5] += bfhi(vx[u].z) * wu[u];
      acc[6] += bflo(vx[u].w) * wu[u];
      acc[7] += bfhi(vx[u].w) * wu[u];
    }
  }
  uint4 hv = *((const uint4*)(H + (size_t)node * 128) + c8);
  float hb[8] = {bflo(hv.x), bfhi(hv.x), bflo(hv.y), bfhi(hv.y),
                 bflo(hv.z), bfhi(hv.z), bflo(hv.w), bfhi(hv.w)};
  float dii = di * di;
  const float* bp = bias + c8 * 8;
  float r[8];
#pragma unroll
  for (int j = 0; j < 8; ++j) {
    float vv = acc[j] * di + hb[j] * dii + bp[j];
    if (do_relu) vv = fmaxf(vv, 0.f);
    r[j] = vv;
  }
  uint4 o;
  o.x = pack2(r[0], r[1]);
  o.y = pack2(r[2], r[3]);
  o.z = pack2(r[4], r[5]);
  o.w = pack2(r[6], r[7]);
  *((uint4*)(Hout + (size_t)node * 128) + c8) = o;
}

// ---------------- global mean pool (batch is sorted), bf16 in ----------------
__device__ inline int lower_bound(const int* a, int n, int v) {
  int lo = 0, hi = n;
  while (lo < hi) {
    int m = (lo + hi) >> 1;
    if (a[m] < v) lo = m + 1; else hi = m;
  }
  return lo;
}

__global__ __launch_bounds__(128) void k_pool(const ushort* __restrict__ H,
                                              const int* __restrict__ batch,
                                              float* __restrict__ f) {
  int g = blockIdx.x;
  int c = threadIdx.x;
  int s = lower_bound(batch, NN, g);
  int e = lower_bound(batch, NN, g + 1);
  float acc = 0.f;
#pragma unroll 4
  for (int i = s; i < e; ++i)
    acc += __uint_as_float(((uint)H[(size_t)i * 128 + c]) << 16);
  f[g * 128 + c] = acc / fmaxf((float)(e - s), 1.0f);
}

// ---------------- MLP as f32 tiled GEMM: Y[M,N] = X[M,K] @ W[K,N] + b ----------------
__global__ __launch_bounds__(256) void k_mgemm(const float* __restrict__ X,
                                               const float* __restrict__ W,
                                               const float* __restrict__ bias,
                                               float* __restrict__ Y,
                                               int M, int K, int N, int do_relu) {
  __shared__ float sA[32][32];  // [k][m]
  __shared__ float sB[32][64];  // [k][n]
  int t = threadIdx.x;
  int tn = t & 15, tm = t >> 4;
  int m0 = blockIdx.y * 32;
  int n0 = blockIdx.x * 64;
  float acc[2][4];
#pragma unroll
  for (int i = 0; i < 2; ++i)
#pragma unroll
    for (int j = 0; j < 4; ++j) acc[i][j] = 0.f;

  for (int kb = 0; kb < K; kb += 32) {
    {
      int r = t >> 3, kq = t & 7;  // 32 rows x 8 float4
      float4 v = *(const float4*)(X + (size_t)(m0 + r) * K + kb + kq * 4);
      sA[kq * 4 + 0][r] = v.x;
      sA[kq * 4 + 1][r] = v.y;
      sA[kq * 4 + 2][r] = v.z;
      sA[kq * 4 + 3][r] = v.w;
    }
#pragma unroll
    for (int l = 0; l < 2; ++l) {
      int idx = t * 2 + l;
      int kr = idx >> 4, nq = idx & 15;
      *(float4*)&sB[kr][nq * 4] = *(const float4*)(W + (size_t)(kb + kr) * N + n0 + nq * 4);
    }
    __syncthreads();
#pragma unroll
    for (int k = 0; k < 32; ++k) {
      float a[2], b[4];
      a[0] = sA[k][tm * 2];
      a[1] = sA[k][tm * 2 + 1];
      *(float4*)b = *(float4*)&sB[k][tn * 4];
#pragma unroll
      for (int i = 0; i < 2; ++i)
#pragma unroll
        for (int j = 0; j < 4; ++j) acc[i][j] += a[i] * b[j];
    }
    __syncthreads();
  }
  float4 bv = *(const float4*)(bias + n0 + tn * 4);
#pragma unroll
  for (int i = 0; i < 2; ++i) {
    float4 o;
    o.x = acc[i][0] + bv.x;
    o.y = acc[i][1] + bv.y;
    o.z = acc[i][2] + bv.z;
    o.w = acc[i][3] + bv.w;
    if (do_relu) {
      o.x = fmaxf(o.x, 0.f);
      o.y = fmaxf(o.y, 0.f);
      o.z = fmaxf(o.z, 0.f);
      o.w = fmaxf(o.w, 0.f);
    }
    *(float4*)(Y + (size_t)(m0 + tm * 2 + i) * N + n0 + tn * 4) = o;
  }
}

extern "C" void kernel_launch(void* const* d_in, const int* in_sizes, int n_in,
                              void* d_out, int out_size, void* d_ws, size_t ws_size,
                              hipStream_t stream) {
  const float* x    = (const float*)d_in[0];
  const int* ei     = (const int*)d_in[1];
  const int* batch  = (const int*)d_in[2];
  const float* W1   = (const float*)d_in[3];  const float* b1  = (const float*)d_in[4];
  const float* W2   = (const float*)d_in[5];  const float* b2  = (const float*)d_in[6];
  const float* W3   = (const float*)d_in[7];  const float* b3  = (const float*)d_in[8];
  const float* Wf1  = (const float*)d_in[9];  const float* bf1 = (const float*)d_in[10];
  const float* Wf2  = (const float*)d_in[11]; const float* bf2 = (const float*)d_in[12];
  const float* Wf3  = (const float*)d_in[13]; const float* bf3 = (const float*)d_in[14];
  const float* Wf4  = (const float*)d_in[15]; const float* bf4 = (const float*)d_in[16];
  const int* src = ei;
  const int* dst = ei + NE;

  char* ws = (char*)d_ws;
  size_t off = 0;
  auto alloc = [&](size_t bytes) {
    void* p = ws + off;
    off += (bytes + 255) & ~(size_t)255;
    return p;
  };
  ushort* B0     = (ushort*)alloc((size_t)NN * 128 * 2);
  ushort* B1     = (ushort*)alloc((size_t)NN * 128 * 2);
  ushort* B2     = (ushort*)alloc((size_t)NN * 128 * 2);
  float* dinv    = (float*)alloc((size_t)NN * 4);
  int*   offsets = (int*)alloc((size_t)(NN + 1) * 4);
  uint*  pedge   = (uint*)alloc((size_t)NE * 4);
  int2*  emeta   = (int2*)alloc((size_t)NE * 8);
  int*   phist   = (int*)alloc((size_t)PPART * 4);
  int*   pbase   = (int*)alloc((size_t)(PPART + 1) * 4);
  int*   pcur    = (int*)alloc((size_t)PPART * 4);
  ushort* wt1    = (ushort*)alloc(128 * 128 * 2);
  ushort* wt2    = (ushort*)alloc(128 * 128 * 2);
  ushort* wt3    = (ushort*)alloc(128 * 128 * 2);
  float* t1      = (float*)alloc((size_t)NG * 512 * 4);
  float* t2      = (float*)alloc((size_t)NG * 256 * 4);
  float* t3      = (float*)alloc((size_t)NG * 128 * 4);

  float* f_out = (float*)d_out;             // [512*128]
  float* z_out = (float*)d_out + NG * HID;  // [512*64]

  // ---- preprocessing ----
  hipMemsetAsync(phist, 0, (size_t)PPART * 4, stream);
  k_hist<<<(NE + EPB - 1) / EPB, 256, 0, stream>>>(dst, phist);
  k_pscan<<<1, 512, 0, stream>>>(phist, pbase, pcur);
  k_part<<<(NE + EPB - 1) / EPB, 256, 0, stream>>>(src, dst, pcur, pedge);
  k_cnt2<<<PPART, 256, 0, stream>>>(pbase, pedge, offsets, dinv);
  k_place<<<PPART, 256, 0, stream>>>(pbase, pedge, offsets, dinv, emeta);

  k_prepW<<<128, 128, 0, stream>>>(W1, wt1);
  k_prepW<<<128, 128, 0, stream>>>(W2, wt2);
  k_prepW<<<128, 128, 0, stream>>>(W3, wt3);

  int gemm_grid = (NN + 63) / 64;
  int agg_grid = (NN + 15) / 16;

  // layer 1 (f32 A path fuses the x cast)
  k_gemmf<<<gemm_grid, 256, 0, stream>>>(x, wt1, B1);
  k_agg<<<agg_grid, 256, 0, stream>>>(B1, b1, dinv, offsets, emeta, B2, 1);
  // layer 2
  k_gemm<<<gemm_grid, 256, 0, stream>>>(B2, wt2, B1);
  k_agg<<<agg_grid, 256, 0, stream>>>(B1, b2, dinv, offsets, emeta, B0, 1);
  // layer 3
  k_gemm<<<gemm_grid, 256, 0, stream>>>(B0, wt3, B1);
  k_agg<<<agg_grid, 256, 0, stream>>>(B1, b3, dinv, offsets, emeta, B2, 0);

  k_pool<<<NG, 128, 0, stream>>>(B2, batch, f_out);

  // MLP head as 4 tiled f32 GEMMs over the whole batch (M=512)
  k_mgemm<<<dim3(8, 16), 256, 0, stream>>>(f_out, Wf1, bf1, t1, NG, 128, 512, 1);
  k_mgemm<<<dim3(4, 16), 256, 0, stream>>>(t1, Wf2, bf2, t2, NG, 512, 256, 1);
  k_mgemm<<<dim3(2, 16), 256, 0, stream>>>(t2, Wf3, bf3, t3, NG, 256, 128, 1);
  k_mgemm<<<dim3(1, 16), 256, 0, stream>>>(t3, Wf4, bf4, z_out, NG, 128, 64, 0);
}

// Round 14
// 367.246 us; speedup vs baseline: 1.1094x; 1.1094x over previous
//
#include <hip/hip_runtime.h>
#include <hip/hip_bf16.h>

#define NN 100000
#define NE 1600000
#define NG 512
#define HID 128
#define PPART 391  // ceil(NN/256) partitions of 256 nodes
#define EPB 4096   // edges per block in k_part
#define CAP 4608   // per-partition window capacity (mean 4096 + 8 sigma)

typedef __attribute__((ext_vector_type(8))) short short8;
typedef __attribute__((ext_vector_type(4))) float floatx4;

__device__ inline ushort f2bf(float f) {
  uint u = __float_as_uint(f);
  u += 0x7fff + ((u >> 16) & 1);
  return (ushort)(u >> 16);
}
__device__ inline uint pack2(float lo, float hi) {
  return (uint)f2bf(lo) | ((uint)f2bf(hi) << 16);
}
__device__ inline float bflo(uint u) { return __uint_as_float(u << 16); }
__device__ inline float bfhi(uint u) { return __uint_as_float(u & 0xffff0000u); }

// ---------------- partition cursor init: pcur[p] = p*CAP ----------------
__global__ void k_pinit(int* __restrict__ pcur) {
  int p = blockIdx.x * 256 + threadIdx.x;
  if (p < PPART) pcur[p] = p * CAP;
}

// ---------------- phase A: append packed edges into strided partition windows ----------------
__global__ __launch_bounds__(256) void k_part(const int* __restrict__ src,
                                              const int* __restrict__ dst,
                                              int* __restrict__ pcur,
                                              uint* __restrict__ pedge) {
  __shared__ int hist[PPART];
  __shared__ int base[PPART];
  int t = threadIdx.x;
  for (int i = t; i < PPART; i += 256) hist[i] = 0;
  __syncthreads();
  int e0 = blockIdx.x * EPB;
  int d_[16];
#pragma unroll
  for (int l = 0; l < 16; ++l) {
    int e = e0 + l * 256 + t;
    if (e < NE) {
      int d = dst[e];
      d_[l] = d;
      atomicAdd(&hist[d >> 8], 1);
    } else {
      d_[l] = -1;
    }
  }
  __syncthreads();
  for (int i = t; i < PPART; i += 256) {
    int h = hist[i];
    base[i] = h ? atomicAdd(&pcur[i], h) : 0;
  }
  __syncthreads();
#pragma unroll
  for (int l = 0; l < 16; ++l) {
    int e = e0 + l * 256 + t;
    if (e < NE) {
      int d = d_[l];
      int s = src[e];
      int pos = atomicAdd(&base[d >> 8], 1);
      pedge[pos] = (uint)s | ((uint)(d & 255) << 24);
    }
  }
}

// ---------------- scan final partition sizes -> pbase[0..PPART] ----------------
__global__ __launch_bounds__(512) void k_pscan(const int* __restrict__ pcur,
                                               int* __restrict__ pbase) {
  __shared__ int ws[8];
  int t = threadIdx.x, lane = t & 63, wid = t >> 6;
  int v = (t < PPART) ? (pcur[t] - t * CAP) : 0;
  int iv = v;
  for (int o = 1; o < 64; o <<= 1) {
    int n = __shfl_up(iv, o, 64);
    if (lane >= o) iv += n;
  }
  if (lane == 63) ws[wid] = iv;
  __syncthreads();
  int add = 0;
#pragma unroll
  for (int w = 0; w < 8; ++w) add += (w < wid) ? ws[w] : 0;
  if (t < PPART) pbase[t] = iv - v + add;
  if (t == 0) {
    int tot = 0;
#pragma unroll
    for (int w = 0; w < 8; ++w) tot += ws[w];
    pbase[PPART] = tot;
  }
}

// ---------------- phase B1: per-partition count+scan -> offsets, dinv ----------------
__global__ __launch_bounds__(256) void k_cnt2(const int* __restrict__ pbase,
                                              const uint* __restrict__ pedge,
                                              int* __restrict__ offsets,
                                              float* __restrict__ dinv) {
  __shared__ int cnt_s[256];
  __shared__ int ws[4];
  int p = blockIdx.x;
  int n0 = p << 8;
  int t = threadIdx.x;
  int lim = NN - n0; if (lim > 256) lim = 256;
  int size = pbase[p + 1] - pbase[p];
  int s = p * CAP;
  cnt_s[t] = 0;
  __syncthreads();
  for (int i = s + t; i < s + size; i += 256) atomicAdd(&cnt_s[pedge[i] >> 24], 1);
  __syncthreads();
  int v = cnt_s[t];
  int lane = t & 63, wid = t >> 6;
  int iv = v;
  for (int o = 1; o < 64; o <<= 1) {
    int n = __shfl_up(iv, o, 64);
    if (lane >= o) iv += n;
  }
  if (lane == 63) ws[wid] = iv;
  __syncthreads();
  int add = 0;
#pragma unroll
  for (int w = 0; w < 4; ++w) add += (w < wid) ? ws[w] : 0;
  int excl = iv - v + add;
  if (t < lim) {
    offsets[n0 + t] = pbase[p] + excl;
    dinv[n0 + t] = 1.0f / sqrtf((float)(v + 1));
  }
  if (p == PPART - 1 && t == 0) offsets[NN] = NE;
}

// ---------------- phase B2: place edges -> emeta {src, bits(dinv[src])} ----------------
__global__ __launch_bounds__(256) void k_place(const int* __restrict__ pbase,
                                               const uint* __restrict__ pedge,
                                               const int* __restrict__ offsets,
                                               const float* __restrict__ dinv,
                                               int2* __restrict__ emeta) {
  __shared__ int cur[256];
  int p = blockIdx.x;
  int n0 = p << 8;
  int t = threadIdx.x;
  int lim = NN - n0; if (lim > 256) lim = 256;
  if (t < lim) cur[t] = offsets[n0 + t];
  __syncthreads();
  int size = pbase[p + 1] - pbase[p];
  int s = p * CAP;
  for (int i = s + t; i < s + size; i += 256) {
    uint pv = pedge[i];
    int srcn = (int)(pv & 0xFFFFFFu);
    int pos = atomicAdd(&cur[pv >> 24], 1);
    int2 m;
    m.x = srcn;
    m.y = __float_as_int(dinv[srcn]);
    emeta[pos] = m;
  }
}

// ---------------- prep W: f32 [128,128] -> bf16 W^T swizzled ----------------
__global__ __launch_bounds__(128) void k_prepW(const float* __restrict__ W,
                                               ushort* __restrict__ wt) {
  int c = blockIdx.x;
  int r = threadIdx.x;
  float v = W[r * 128 + c];
  wt[c * 128 + (((r >> 3) ^ (c & 15)) << 3) + (r & 7)] = f2bf(v);
}

// ---------------- bf16 MFMA GEMM (bf16 A): H = X @ W ----------------
__global__ __launch_bounds__(256) void k_gemm(const ushort* __restrict__ Xb,
                                              const ushort* __restrict__ wt,
                                              ushort* __restrict__ Hb) {
  __shared__ ushort sW[128 * 128];
  int t = threadIdx.x;
#pragma unroll
  for (int l = 0; l < 8; ++l) {
    int idx = t + l * 256;
    ((uint4*)sW)[idx] = ((const uint4*)wt)[idx];
  }
  __syncthreads();
  int wid = t >> 6, lane = t & 63;
  int row0 = blockIdx.x * 64 + wid * 16;
  int arow = row0 + (lane & 15);
  if (arow >= NN) arow = NN - 1;
  const ushort* aptr = Xb + (size_t)arow * 128 + ((lane >> 4) * 8);
  floatx4 acc[8];
#pragma unroll
  for (int n = 0; n < 8; ++n) acc[n] = (floatx4)(0.f);
#pragma unroll
  for (int kb = 0; kb < 4; ++kb) {
    short8 a = *(const short8*)(aptr + kb * 32);
    int kslot = kb * 4 + (lane >> 4);
#pragma unroll
    for (int n = 0; n < 8; ++n) {
      int col = n * 16 + (lane & 15);
      const ushort* bp = sW + col * 128 + ((kslot ^ (col & 15)) << 3);
      short8 b = *(const short8*)bp;
      acc[n] = __builtin_amdgcn_mfma_f32_16x16x32_bf16(a, b, acc[n], 0, 0, 0);
    }
  }
  int srow_base = row0 + (lane >> 4) * 4;
#pragma unroll
  for (int r = 0; r < 4; ++r) {
    int grow = srow_base + r;
    if (grow < NN) {
      ushort* out = Hb + (size_t)grow * 128 + (lane & 15);
#pragma unroll
      for (int n = 0; n < 8; ++n) out[n * 16] = f2bf(acc[n][r]);
    }
  }
}

// ---------------- bf16 MFMA GEMM, f32 A input (layer 1; fuses the cast) ----------------
__global__ __launch_bounds__(256) void k_gemmf(const float* __restrict__ Xf,
                                               const ushort* __restrict__ wt,
                                               ushort* __restrict__ Hb) {
  __shared__ ushort sW[128 * 128];
  int t = threadIdx.x;
#pragma unroll
  for (int l = 0; l < 8; ++l) {
    int idx = t + l * 256;
    ((uint4*)sW)[idx] = ((const uint4*)wt)[idx];
  }
  __syncthreads();
  int wid = t >> 6, lane = t & 63;
  int row0 = blockIdx.x * 64 + wid * 16;
  int arow = row0 + (lane & 15);
  if (arow >= NN) arow = NN - 1;
  const float* aptr = Xf + (size_t)arow * 128 + ((lane >> 4) * 8);
  floatx4 acc[8];
#pragma unroll
  for (int n = 0; n < 8; ++n) acc[n] = (floatx4)(0.f);
#pragma unroll
  for (int kb = 0; kb < 4; ++kb) {
    float4 f0 = *(const float4*)(aptr + kb * 32);
    float4 f1 = *(const float4*)(aptr + kb * 32 + 4);
    union { uint4 u; short8 s; } av;
    av.u.x = pack2(f0.x, f0.y);
    av.u.y = pack2(f0.z, f0.w);
    av.u.z = pack2(f1.x, f1.y);
    av.u.w = pack2(f1.z, f1.w);
    short8 a = av.s;
    int kslot = kb * 4 + (lane >> 4);
#pragma unroll
    for (int n = 0; n < 8; ++n) {
      int col = n * 16 + (lane & 15);
      const ushort* bp = sW + col * 128 + ((kslot ^ (col & 15)) << 3);
      short8 b = *(const short8*)bp;
      acc[n] = __builtin_amdgcn_mfma_f32_16x16x32_bf16(a, b, acc[n], 0, 0, 0);
    }
  }
  int srow_base = row0 + (lane >> 4) * 4;
#pragma unroll
  for (int r = 0; r < 4; ++r) {
    int grow = srow_base + r;
    if (grow < NN) {
      ushort* out = Hb + (size_t)grow * 128 + (lane & 15);
#pragma unroll
      for (int n = 0; n < 8; ++n) out[n * 16] = f2bf(acc[n][r]);
    }
  }
}

// ---------------- pull aggregation: per-lane metadata + shfl broadcast (R11) ----------------
// 16-lane group per node; lane c8 holds edge-meta for edge s+c8 (+16 per chunk).
__global__ __launch_bounds__(256) void k_agg(const ushort* __restrict__ H,
                                             const float* __restrict__ bias,
                                             const float* __restrict__ dinv,
                                             const int* __restrict__ offsets,
                                             const int2* __restrict__ emeta,
                                             ushort* __restrict__ Hout, int do_relu) {
  int node = blockIdx.x * 16 + (threadIdx.x >> 4);
  if (node >= NN) return;
  int lane = threadIdx.x & 63;
  int c8 = lane & 15;         // 16B slot; channels c8*8 .. c8*8+7
  int gbase = lane & 48;      // 16-lane group base within wave
  float di = dinv[node];
  int s = offsets[node], e = offsets[node + 1];
  float acc[8];
#pragma unroll
  for (int j = 0; j < 8; ++j) acc[j] = 0.f;
  for (int i = s; i < e; i += 16) {
    int idx = i + c8;
    bool vld = idx < e;
    int2 m = emeta[vld ? idx : s];
    int msrc = m.x;
    float mw = vld ? __int_as_float(m.y) : 0.0f;
#pragma unroll
    for (int half = 0; half < 2; ++half) {
      int sxu[8];
      float wu[8];
#pragma unroll
      for (int u = 0; u < 8; ++u) {
        int sl = gbase + half * 8 + u;
        sxu[u] = __shfl(msrc, sl, 64);
        wu[u] = __shfl(mw, sl, 64);
      }
      uint4 vx[8];
#pragma unroll
      for (int u = 0; u < 8; ++u)
        vx[u] = *((const uint4*)(H + (size_t)sxu[u] * 128) + c8);
#pragma unroll
      for (int u = 0; u < 8; ++u) {
        acc[0] += bflo(vx[u].x) * wu[u];
        acc[1] += bfhi(vx[u].x) * wu[u];
        acc[2] += bflo(vx[u].y) * wu[u];
        acc[3] += bfhi(vx[u].y) * wu[u];
        acc[4] += bflo(vx[u].z) * wu[u];
        acc[5] += bfhi(vx[u].z) * wu[u];
        acc[6] += bflo(vx[u].w) * wu[u];
        acc[7] += bfhi(vx[u].w) * wu[u];
      }
    }
  }
  uint4 hv = *((const uint4*)(H + (size_t)node * 128) + c8);
  float hb[8] = {bflo(hv.x), bfhi(hv.x), bflo(hv.y), bfhi(hv.y),
                 bflo(hv.z), bfhi(hv.z), bflo(hv.w), bfhi(hv.w)};
  float dii = di * di;
  const float* bp = bias + c8 * 8;
  float r[8];
#pragma unroll
  for (int j = 0; j < 8; ++j) {
    float vv = acc[j] * di + hb[j] * dii + bp[j];
    if (do_relu) vv = fmaxf(vv, 0.f);
    r[j] = vv;
  }
  uint4 o;
  o.x = pack2(r[0], r[1]);
  o.y = pack2(r[2], r[3]);
  o.z = pack2(r[4], r[5]);
  o.w = pack2(r[6], r[7]);
  *((uint4*)(Hout + (size_t)node * 128) + c8) = o;
}

// ---------------- global mean pool (batch is sorted), bf16 in ----------------
__device__ inline int lower_bound(const int* a, int n, int v) {
  int lo = 0, hi = n;
  while (lo < hi) {
    int m = (lo + hi) >> 1;
    if (a[m] < v) lo = m + 1; else hi = m;
  }
  return lo;
}

__global__ __launch_bounds__(128) void k_pool(const ushort* __restrict__ H,
                                              const int* __restrict__ batch,
                                              float* __restrict__ f) {
  int g = blockIdx.x;
  int c = threadIdx.x;
  int s = lower_bound(batch, NN, g);
  int e = lower_bound(batch, NN, g + 1);
  float acc = 0.f;
#pragma unroll 4
  for (int i = s; i < e; ++i)
    acc += __uint_as_float(((uint)H[(size_t)i * 128 + c]) << 16);
  f[g * 128 + c] = acc / fmaxf((float)(e - s), 1.0f);
}

// ---------------- MLP as f32 tiled GEMM: Y[M,N] = X[M,K] @ W[K,N] + b ----------------
__global__ __launch_bounds__(256) void k_mgemm(const float* __restrict__ X,
                                               const float* __restrict__ W,
                                               const float* __restrict__ bias,
                                               float* __restrict__ Y,
                                               int M, int K, int N, int do_relu) {
  __shared__ float sA[32][32];  // [k][m]
  __shared__ float sB[32][64];  // [k][n]
  int t = threadIdx.x;
  int tn = t & 15, tm = t >> 4;
  int m0 = blockIdx.y * 32;
  int n0 = blockIdx.x * 64;
  float acc[2][4];
#pragma unroll
  for (int i = 0; i < 2; ++i)
#pragma unroll
    for (int j = 0; j < 4; ++j) acc[i][j] = 0.f;

  for (int kb = 0; kb < K; kb += 32) {
    {
      int r = t >> 3, kq = t & 7;  // 32 rows x 8 float4
      float4 v = *(const float4*)(X + (size_t)(m0 + r) * K + kb + kq * 4);
      sA[kq * 4 + 0][r] = v.x;
      sA[kq * 4 + 1][r] = v.y;
      sA[kq * 4 + 2][r] = v.z;
      sA[kq * 4 + 3][r] = v.w;
    }
#pragma unroll
    for (int l = 0; l < 2; ++l) {
      int idx = t * 2 + l;
      int kr = idx >> 4, nq = idx & 15;
      *(float4*)&sB[kr][nq * 4] = *(const float4*)(W + (size_t)(kb + kr) * N + n0 + nq * 4);
    }
    __syncthreads();
#pragma unroll
    for (int k = 0; k < 32; ++k) {
      float a[2], b[4];
      a[0] = sA[k][tm * 2];
      a[1] = sA[k][tm * 2 + 1];
      *(float4*)b = *(float4*)&sB[k][tn * 4];
#pragma unroll
      for (int i = 0; i < 2; ++i)
#pragma unroll
        for (int j = 0; j < 4; ++j) acc[i][j] += a[i] * b[j];
    }
    __syncthreads();
  }
  float4 bv = *(const float4*)(bias + n0 + tn * 4);
#pragma unroll
  for (int i = 0; i < 2; ++i) {
    float4 o;
    o.x = acc[i][0] + bv.x;
    o.y = acc[i][1] + bv.y;
    o.z = acc[i][2] + bv.z;
    o.w = acc[i][3] + bv.w;
    if (do_relu) {
      o.x = fmaxf(o.x, 0.f);
      o.y = fmaxf(o.y, 0.f);
      o.z = fmaxf(o.z, 0.f);
      o.w = fmaxf(o.w, 0.f);
    }
    *(float4*)(Y + (size_t)(m0 + tm * 2 + i) * N + n0 + tn * 4) = o;
  }
}

extern "C" void kernel_launch(void* const* d_in, const int* in_sizes, int n_in,
                              void* d_out, int out_size, void* d_ws, size_t ws_size,
                              hipStream_t stream) {
  const float* x    = (const float*)d_in[0];
  const int* ei     = (const int*)d_in[1];
  const int* batch  = (const int*)d_in[2];
  const float* W1   = (const float*)d_in[3];  const float* b1  = (const float*)d_in[4];
  const float* W2   = (const float*)d_in[5];  const float* b2  = (const float*)d_in[6];
  const float* W3   = (const float*)d_in[7];  const float* b3  = (const float*)d_in[8];
  const float* Wf1  = (const float*)d_in[9];  const float* bf1 = (const float*)d_in[10];
  const float* Wf2  = (const float*)d_in[11]; const float* bf2 = (const float*)d_in[12];
  const float* Wf3  = (const float*)d_in[13]; const float* bf3 = (const float*)d_in[14];
  const float* Wf4  = (const float*)d_in[15]; const float* bf4 = (const float*)d_in[16];
  const int* src = ei;
  const int* dst = ei + NE;

  char* ws = (char*)d_ws;
  size_t off = 0;
  auto alloc = [&](size_t bytes) {
    void* p = ws + off;
    off += (bytes + 255) & ~(size_t)255;
    return p;
  };
  ushort* B0     = (ushort*)alloc((size_t)NN * 128 * 2);
  ushort* B1     = (ushort*)alloc((size_t)NN * 128 * 2);
  ushort* B2     = (ushort*)alloc((size_t)NN * 128 * 2);
  float* dinv    = (float*)alloc((size_t)NN * 4);
  int*   offsets = (int*)alloc((size_t)(NN + 1) * 4);
  uint*  pedge   = (uint*)alloc((size_t)PPART * CAP * 4);
  int2*  emeta   = (int2*)alloc((size_t)NE * 8);
  int*   pbase   = (int*)alloc((size_t)(PPART + 1) * 4);
  int*   pcur    = (int*)alloc((size_t)PPART * 4);
  ushort* wt1    = (ushort*)alloc(128 * 128 * 2);
  ushort* wt2    = (ushort*)alloc(128 * 128 * 2);
  ushort* wt3    = (ushort*)alloc(128 * 128 * 2);
  float* t1      = (float*)alloc((size_t)NG * 512 * 4);
  float* t2      = (float*)alloc((size_t)NG * 256 * 4);
  float* t3      = (float*)alloc((size_t)NG * 128 * 4);

  float* f_out = (float*)d_out;             // [512*128]
  float* z_out = (float*)d_out + NG * HID;  // [512*64]

  // ---- preprocessing: direct append -> scan -> count -> place ----
  k_pinit<<<(PPART + 255) / 256, 256, 0, stream>>>(pcur);
  k_part<<<(NE + EPB - 1) / EPB, 256, 0, stream>>>(src, dst, pcur, pedge);
  k_pscan<<<1, 512, 0, stream>>>(pcur, pbase);
  k_cnt2<<<PPART, 256, 0, stream>>>(pbase, pedge, offsets, dinv);
  k_place<<<PPART, 256, 0, stream>>>(pbase, pedge, offsets, dinv, emeta);

  k_prepW<<<128, 128, 0, stream>>>(W1, wt1);
  k_prepW<<<128, 128, 0, stream>>>(W2, wt2);
  k_prepW<<<128, 128, 0, stream>>>(W3, wt3);

  int gemm_grid = (NN + 63) / 64;
  int agg_grid = (NN + 15) / 16;

  // layer 1 (f32 A path fuses the x cast)
  k_gemmf<<<gemm_grid, 256, 0, stream>>>(x, wt1, B1);
  k_agg<<<agg_grid, 256, 0, stream>>>(B1, b1, dinv, offsets, emeta, B2, 1);
  // layer 2
  k_gemm<<<gemm_grid, 256, 0, stream>>>(B2, wt2, B1);
  k_agg<<<agg_grid, 256, 0, stream>>>(B1, b2, dinv, offsets, emeta, B0, 1);
  // layer 3
  k_gemm<<<gemm_grid, 256, 0, stream>>>(B0, wt3, B1);
  k_agg<<<agg_grid, 256, 0, stream>>>(B1, b3, dinv, offsets, emeta, B2, 0);

  k_pool<<<NG, 128, 0, stream>>>(B2, batch, f_out);

  // MLP head as 4 tiled f32 GEMMs over the whole batch (M=512)
  k_mgemm<<<dim3(8, 16), 256, 0, stream>>>(f_out, Wf1, bf1, t1, NG, 128, 512, 1);
  k_mgemm<<<dim3(4, 16), 256, 0, stream>>>(t1, Wf2, bf2, t2, NG, 512, 256, 1);
  k_mgemm<<<dim3(2, 16), 256, 0, stream>>>(t2, Wf3, bf3, t3, NG, 256, 128, 1);
  k_mgemm<<<dim3(1, 16), 256, 0, stream>>>(t3, Wf4, bf4, z_out, NG, 128, 64, 0);
}